// Round 9
// baseline (30418.976 us; speedup 1.0000x reference)
//
#include <hip/hip_runtime.h>

#define Bb 8
#define Nn 2048
#define Dd 512
#define KT 32            // keys per LDS tile
#define NT (Nn / KT)     // 64 tiles

// R2's audited pure-VALU f32 flash attention. ONLY change vs R2: the output
// buffer is FLOAT32 (the reference returns f32; the "bf16" in the harness
// assert label is a hardcoded string). We store f32.
//   block = 512 threads = 8 waves; wave handles 4 q-rows.
//   lane = qr*16 + dp: qr = lane>>4, dp = lane&15 (32-float d-slice per lane).
__global__ __launch_bounds__(512, 1)
void attn_valu_kernel(const float* __restrict__ X, const int* __restrict__ mask,
                      float* __restrict__ out) {
  __shared__ float sX[KT * Dd];  // 32 keys x 512 d, f32 = 64 KB

  const int tid  = threadIdx.x;
  const int wave = tid >> 6;      // 0..7
  const int lane = tid & 63;
  const int qr   = lane >> 4;     // 0..3
  const int dp   = lane & 15;     // 0..15
  const int b    = blockIdx.y;
  const int qrow = blockIdx.x * 32 + wave * 4 + qr;
  const float scale = 0.044194173824159216f;  // 1/sqrt(512)

  float q[32];
  {
    const float* qp = X + ((size_t)b * Nn + qrow) * Dd + dp * 32;
#pragma unroll
    for (int i = 0; i < 8; ++i) {
      float4 v = *(const float4*)(qp + i * 4);
      q[i * 4 + 0] = v.x; q[i * 4 + 1] = v.y;
      q[i * 4 + 2] = v.z; q[i * 4 + 3] = v.w;
    }
  }

  const float bias = (1.0f - (float)mask[b * Nn + qrow]) * 1e9f;

  float o[32];
#pragma unroll
  for (int i = 0; i < 32; ++i) o[i] = 0.0f;
  float m = -1e30f, l = 0.0f;

  for (int t = 0; t < NT; ++t) {
    __syncthreads();
    {
      const float* src = X + ((size_t)b * Nn + t * KT) * Dd;
#pragma unroll
      for (int it = 0; it < 8; ++it) {
        int idx = it * 512 + tid;
        float4 v = *(const float4*)(src + idx * 4);
        *(float4*)(sX + idx * 4) = v;
      }
    }
    __syncthreads();

    for (int j = 0; j < KT; ++j) {
      const float* xr = sX + j * Dd + dp * 32;
      float xv[32];
#pragma unroll
      for (int i0 = 0; i0 < 8; ++i0) {
        int ii = (i0 + dp) & 7;
        float4 v = *(const float4*)(xr + ii * 4);
        xv[ii * 4 + 0] = v.x; xv[ii * 4 + 1] = v.y;
        xv[ii * 4 + 2] = v.z; xv[ii * 4 + 3] = v.w;
      }
      float s = 0.0f;
#pragma unroll
      for (int i = 0; i < 32; ++i) s = fmaf(q[i], xv[i], s);
#pragma unroll
      for (int off = 1; off < 16; off <<= 1) s += __shfl_xor(s, off);

      // f32: masked rows collapse to exactly -1e9 (|s*scale| < 32 = half-ulp
      // of 1e9), reproducing the reference's f32 collapse to uniform attention.
      s = s * scale - bias;

      if (s > m) {
        float al = __expf(m - s);
        l *= al;
#pragma unroll
        for (int i = 0; i < 32; ++i) o[i] *= al;
        m = s;
      }
      float p = __expf(s - m);
      l += p;
#pragma unroll
      for (int i = 0; i < 32; ++i) o[i] = fmaf(p, xv[i], o[i]);
    }
  }

  // Epilogue: normalize, store FLOAT32.
  const float inv = 1.0f / l;
  float* op = out + ((size_t)b * Nn + qrow) * Dd + dp * 32;
#pragma unroll
  for (int g = 0; g < 8; ++g) {
    float4 w;
    w.x = o[g * 4 + 0] * inv;
    w.y = o[g * 4 + 1] * inv;
    w.z = o[g * 4 + 2] * inv;
    w.w = o[g * 4 + 3] * inv;
    *(float4*)(op + g * 4) = w;
  }
}

extern "C" void kernel_launch(void* const* d_in, const int* in_sizes, int n_in,
                              void* d_out, int out_size, void* d_ws, size_t ws_size,
                              hipStream_t stream) {
  (void)in_sizes; (void)n_in; (void)out_size; (void)d_ws; (void)ws_size;
  const float* X    = (const float*)d_in[0];
  const int*   mask = (const int*)d_in[1];
  float* out = (float*)d_out;

  attn_valu_kernel<<<dim3(Nn / 32, Bb), 512, 0, stream>>>(X, mask, out);
}

// Round 10
// 979.459 us; speedup vs baseline: 31.0569x; 31.0569x over previous
//
#include <hip/hip_runtime.h>

#define Bb 8
#define Nn 2048
#define Dd 512
#define KVBLK 64
#define NTILE (Nn / KVBLK)
#define PP 72

typedef __attribute__((ext_vector_type(8))) short bf8;
typedef __attribute__((ext_vector_type(4))) float f4;

struct __align__(16) U8 { unsigned short s[8]; };

__device__ __forceinline__ unsigned short f2bf(float f) {
  union { float f; unsigned u; } v; v.f = f;
  unsigned r = v.u + 0x7fffu + ((v.u >> 16) & 1u);
  return (unsigned short)(r >> 16);
}

__global__ __launch_bounds__(256)
void cast_bf16_kernel(const float* __restrict__ X, unsigned short* __restrict__ Y) {
  size_t i = ((size_t)blockIdx.x * 256 + threadIdx.x) * 4;
  float4 v = *(const float4*)(X + i);
  union { unsigned long long u; unsigned short s[4]; } w;
  w.s[0] = f2bf(v.x); w.s[1] = f2bf(v.y);
  w.s[2] = f2bf(v.z); w.s[3] = f2bf(v.w);
  *(unsigned long long*)(Y + i) = w.u;
}

// MFMA flash attention. f32 inputs (cast to bf16 via prepass into d_ws when
// available), f32 output. block = 256 = 4 waves; wave owns 16 q-rows;
// KV tiles of 64 keys. lane = lg*16 + ll. MFMA 16x16x32 bf16;
// C/D layout: col = ll, row = lg*4 + reg (m89-verified).
template <bool USEB>
__global__ __launch_bounds__(256, 1)
void attn_kernel(const float* __restrict__ Xf, const unsigned short* __restrict__ Xb,
                 const int* __restrict__ mask, float* __restrict__ out) {
  // K tile [key][d], 16B slots XOR-swizzled by key&7 -> conflict-free b128 reads
  __shared__ unsigned short sK[KVBLK * Dd];    // 64 KB
  // V tile transposed [d][key], granule-swizzled -> conflict-free b128 reads
  __shared__ unsigned short sVt[Dd * KVBLK];   // 64 KB
  __shared__ unsigned short sP[4][16 * PP];    // per-wave P round-trip buffers

  const int tid  = threadIdx.x;
  const int wave = tid >> 6;
  const int lane = tid & 63;
  const int lg = lane >> 4;   // 0..3
  const int ll = lane & 15;   // 0..15
  const int b  = blockIdx.y;
  const int q0 = blockIdx.x * 64 + wave * 16;  // this wave's 16 q-rows

  // ---- Q fragments: A-layout row = ll, k = ch*32 + lg*8 + e ----
  bf8 qf[16];
  {
    const size_t qoff = ((size_t)b * Nn + q0 + ll) * Dd;
#pragma unroll
    for (int ch = 0; ch < 16; ++ch) {
      int doff = ch * 32 + lg * 8;
      if (USEB) {
        qf[ch] = *(const bf8*)(Xb + qoff + doff);
      } else {
        float4 a = *(const float4*)(Xf + qoff + doff);
        float4 c = *(const float4*)(Xf + qoff + doff + 4);
        bf8 t;
        t[0] = (short)f2bf(a.x); t[1] = (short)f2bf(a.y);
        t[2] = (short)f2bf(a.z); t[3] = (short)f2bf(a.w);
        t[4] = (short)f2bf(c.x); t[5] = (short)f2bf(c.y);
        t[6] = (short)f2bf(c.z); t[7] = (short)f2bf(c.w);
        qf[ch] = t;
      }
    }
  }

  // Per-query bias; C-layout row r -> absolute q-row q0 + lg*4 + r.
  float bias[4];
#pragma unroll
  for (int r = 0; r < 4; ++r)
    bias[r] = (1.0f - (float)mask[b * Nn + q0 + lg * 4 + r]) * 1e9f;

  float m[4], lsum[4];
  f4 o[32];
#pragma unroll
  for (int r = 0; r < 4; ++r) { m[r] = -1e30f; lsum[r] = 0.0f; }
#pragma unroll
  for (int ct = 0; ct < 32; ++ct) o[ct] = (f4){0.f, 0.f, 0.f, 0.f};

  const float scale = 0.044194173824159216f;  // 1/sqrt(512)

  for (int t = 0; t < NTILE; ++t) {
    __syncthreads();
    // ---- stage 64 keys x 512 d into sK (swizzled) + sVt (transposed) ----
    const size_t base = ((size_t)b * Nn + t * KVBLK) * Dd;
#pragma unroll
    for (int it = 0; it < 16; ++it) {
      int idx = it * 256 + tid;     // 16B-bf16-chunk index, 0..4095
      int key = idx >> 6;           // 64 chunks per key row
      int c   = idx & 63;           // chunk within row; d0 = c*8
      U8 v;
      if (USEB) {
        v = *(const U8*)(Xb + base + key * Dd + c * 8);
      } else {
        const float* sp = Xf + base + key * Dd + c * 8;
        float4 a = *(const float4*)(sp);
        float4 d2 = *(const float4*)(sp + 4);
        v.s[0] = f2bf(a.x); v.s[1] = f2bf(a.y); v.s[2] = f2bf(a.z); v.s[3] = f2bf(a.w);
        v.s[4] = f2bf(d2.x); v.s[5] = f2bf(d2.y); v.s[6] = f2bf(d2.z); v.s[7] = f2bf(d2.w);
      }
      // sK: chunk c -> slot c ^ (key&7)  (16B store, 2-way = free)
      *(U8*)(sK + key * 512 + ((c ^ (key & 7)) << 3)) = v;
      // sVt: element (dd = c*8+j, key) -> elem dd*64 + gran*8 + (key&7)
      int ko = key >> 3, k7 = key & 7;
#pragma unroll
      for (int j = 0; j < 8; ++j) {
        int dd = c * 8 + j;
        int gran = ko ^ j ^ (c & 7);
        sVt[dd * 64 + gran * 8 + k7] = v.s[j];
      }
    }
    __syncthreads();

    // ---- QK^T: S[16 q x 64 keys] ----
    f4 s[4];
#pragma unroll
    for (int cc = 0; cc < 4; ++cc) s[cc] = (f4){0.f, 0.f, 0.f, 0.f};
#pragma unroll
    for (int ch = 0; ch < 16; ++ch) {
#pragma unroll
      for (int cc = 0; cc < 4; ++cc) {
        int key = cc * 16 + ll;
        int slot = (ch * 4 + lg) ^ (key & 7);
        bf8 kf = *(const bf8*)(sK + key * 512 + slot * 8);
        s[cc] = __builtin_amdgcn_mfma_f32_16x16x32_bf16(qf[ch], kf, s[cc], 0, 0, 0);
      }
    }

    // ---- online softmax (C layout: col = ll, row = lg*4+r) ----
    float e[4][4];
#pragma unroll
    for (int cc = 0; cc < 4; ++cc)
#pragma unroll
      for (int r = 0; r < 4; ++r)
        e[cc][r] = s[cc][r] * scale - bias[r];  // f32: masked rows -> exactly -1e9

    float tm[4];
#pragma unroll
    for (int r = 0; r < 4; ++r)
      tm[r] = fmaxf(fmaxf(e[0][r], e[1][r]), fmaxf(e[2][r], e[3][r]));
#pragma unroll
    for (int off = 1; off < 16; off <<= 1)
#pragma unroll
      for (int r = 0; r < 4; ++r)
        tm[r] = fmaxf(tm[r], __shfl_xor(tm[r], off));

    float mn[4];
    bool change = false;
#pragma unroll
    for (int r = 0; r < 4; ++r) { mn[r] = fmaxf(m[r], tm[r]); change = change || (mn[r] > m[r]); }
    if (__any(change)) {
#pragma unroll
      for (int r = 0; r < 4; ++r) {
        float al = __expf(m[r] - mn[r]);
        lsum[r] *= al;
        m[r] = mn[r];
#pragma unroll
        for (int ct = 0; ct < 32; ++ct) o[ct][r] *= al;
      }
    }

    float ts[4] = {0.f, 0.f, 0.f, 0.f};
    unsigned short pb[4][4];
#pragma unroll
    for (int cc = 0; cc < 4; ++cc)
#pragma unroll
      for (int r = 0; r < 4; ++r) {
        float p = __expf(e[cc][r] - m[r]);
        ts[r] += p;
        pb[cc][r] = f2bf(p);
      }
#pragma unroll
    for (int off = 1; off < 16; off <<= 1)
#pragma unroll
      for (int r = 0; r < 4; ++r)
        ts[r] += __shfl_xor(ts[r], off);
#pragma unroll
    for (int r = 0; r < 4; ++r) lsum[r] += ts[r];

    // ---- P -> per-wave LDS (C-layout write, A-layout read; same wave) ----
    unsigned short* Pw = sP[wave];
#pragma unroll
    for (int cc = 0; cc < 4; ++cc)
#pragma unroll
      for (int r = 0; r < 4; ++r)
        Pw[(lg * 4 + r) * PP + cc * 16 + ll] = pb[cc][r];

    // ---- PV: O[16 x 512] += P[16 x 64] * V[64 x 512] ----
#pragma unroll
    for (int kc = 0; kc < 2; ++kc) {
      bf8 af = *(const bf8*)(Pw + ll * PP + kc * 32 + lg * 8);
#pragma unroll
      for (int ct = 0; ct < 32; ++ct) {
        int d = ct * 16 + ll;
        int gran = (kc * 4 + lg) ^ (d & 7) ^ ((d >> 3) & 7);
        bf8 vf = *(const bf8*)(sVt + d * 64 + gran * 8);
        o[ct] = __builtin_amdgcn_mfma_f32_16x16x32_bf16(af, vf, o[ct], 0, 0, 0);
      }
    }
  }

  // ---- epilogue: normalize, store f32 ----
  float inv[4];
#pragma unroll
  for (int r = 0; r < 4; ++r) inv[r] = 1.0f / lsum[r];
#pragma unroll
  for (int ct = 0; ct < 32; ++ct)
#pragma unroll
    for (int r = 0; r < 4; ++r) {
      size_t row = (size_t)b * Nn + q0 + lg * 4 + r;
      out[row * Dd + ct * 16 + ll] = o[ct][r] * inv[r];
    }
}

extern "C" void kernel_launch(void* const* d_in, const int* in_sizes, int n_in,
                              void* d_out, int out_size, void* d_ws, size_t ws_size,
                              hipStream_t stream) {
  (void)in_sizes; (void)n_in; (void)out_size;
  const float* X  = (const float*)d_in[0];
  const int* mask = (const int*)d_in[1];
  float* out = (float*)d_out;

  const size_t need = (size_t)Bb * Nn * Dd * 2;
  if (ws_size >= need) {
    unsigned short* Xb = (unsigned short*)d_ws;
    cast_bf16_kernel<<<(Bb * Nn * Dd) / (256 * 4), 256, 0, stream>>>(X, Xb);
    attn_kernel<true><<<dim3(Nn / 64, Bb), 256, 0, stream>>>(X, Xb, mask, out);
  } else {
    attn_kernel<false><<<dim3(Nn / 64, Bb), 256, 0, stream>>>(X, nullptr, mask, out);
  }
}

// Round 11
// 342.997 us; speedup vs baseline: 88.6858x; 2.8556x over previous
//
#include <hip/hip_runtime.h>

#define Bb 8
#define Nn 2048
#define Dd 512

// fast path: KV tiles of 32 keys, precomputed LDS images, double-buffered
#define KV 32
#define NT (Nn / KV)     // 64 tiles
#define PP2 40           // sP row stride (elements, 80B = 16B-aligned)

// fallback: R10 structure (KV=64, in-kernel convert)
#define KVF 64
#define NTF (Nn / KVF)
#define PPF 72

typedef __attribute__((ext_vector_type(8))) short bf8;
typedef __attribute__((ext_vector_type(4))) float f4;
struct __align__(16) U8 { unsigned short s[8]; };

__device__ __forceinline__ unsigned short f2bf(float f) {
  union { float f; unsigned u; } v; v.f = f;
  unsigned r = v.u + 0x7fffu + ((v.u >> 16) & 1u);
  return (unsigned short)(r >> 16);
}

// ---------------------------------------------------------------------------
// Transform: build per-(b,tile) LDS images in ws, ONCE.
// Image (64KB = 32768 ushorts): [sK 16384][sVt 16384]
//   sK : key*512 + ((c ^ (key&7))<<3), c = d>>3      (swizzled row-major)
//   sVt: 16384 + d*32 + ((g ^ ((d>>1)&3))<<3), g = key>>3  (swizzled transpose)
// ---------------------------------------------------------------------------
__global__ __launch_bounds__(256)
void build_images(const float* __restrict__ X, unsigned short* __restrict__ W) {
  __shared__ float sT[KV * Dd];  // 64 KB
  const int t = blockIdx.x, b = blockIdx.y, tid = threadIdx.x;
  const float* src = X + ((size_t)b * Nn + t * KV) * Dd;
#pragma unroll
  for (int i = 0; i < 16; ++i) {
    int idx = i * 256 + tid;                       // float4 idx 0..4095
    *(float4*)(sT + idx * 4) = *(const float4*)(src + idx * 4);
  }
  __syncthreads();
  unsigned short* img = W + ((size_t)(b * NT + t) << 15);
  // sK image
#pragma unroll
  for (int i = 0; i < 8; ++i) {
    int idx = i * 256 + tid;                       // 0..2047
    int key = idx >> 6, c = idx & 63;
    const float* p = sT + key * Dd + c * 8;
    U8 v;
#pragma unroll
    for (int j = 0; j < 8; ++j) v.s[j] = f2bf(p[j]);
    *(U8*)(img + key * 512 + ((c ^ (key & 7)) << 3)) = v;
  }
  // sVt image
#pragma unroll
  for (int i = 0; i < 8; ++i) {
    int idx = i * 256 + tid;                       // 0..2047
    int d = idx >> 2, g = idx & 3;
    U8 v;
#pragma unroll
    for (int e = 0; e < 8; ++e) v.s[e] = f2bf(sT[(g * 8 + e) * Dd + d]);
    *(U8*)(img + 16384 + d * 32 + ((g ^ ((d >> 1) & 3)) << 3)) = v;
  }
}

// ---------------------------------------------------------------------------
// Fast attention: 4 waves x 16 q-rows, KV=32, double-buffered image staging.
// ---------------------------------------------------------------------------
__global__ __launch_bounds__(256, 1)
void attn_fast(const unsigned short* __restrict__ W, const int* __restrict__ mask,
               float* __restrict__ out) {
  __shared__ unsigned short sbuf[2][32768];        // 2 x 64 KB images
  __shared__ unsigned short sP[4][16 * PP2];       // 5 KB

  const int tid  = threadIdx.x;
  const int wave = tid >> 6, lane = tid & 63;
  const int lg = lane >> 4, ll = lane & 15;
  const int bid = blockIdx.x;
  const int b  = bid & 7;                          // XCD-batch affinity
  const int qb = bid >> 3;                         // 0..31
  const int q0 = qb * 64 + wave * 16;
  const float scale = 0.044194173824159216f;       // 1/sqrt(512)

  // Q fragments from the sK images (bf16, same layout math as K reads)
  bf8 qf[16];
  {
    int qrow = q0 + ll;
    const unsigned short* qimg = W + ((size_t)(b * NT + (qrow >> 5)) << 15);
    int key = qrow & 31;
#pragma unroll
    for (int ch = 0; ch < 16; ++ch) {
      int c = ch * 4 + lg;
      qf[ch] = *(const bf8*)(qimg + key * 512 + ((c ^ (key & 7)) << 3));
    }
  }

  float bias[4];
#pragma unroll
  for (int r = 0; r < 4; ++r)
    bias[r] = (1.0f - (float)mask[b * Nn + q0 + lg * 4 + r]) * 1e9f;

  float m[4], lsum[4];
  f4 o[32];
#pragma unroll
  for (int r = 0; r < 4; ++r) { m[r] = -1e30f; lsum[r] = 0.0f; }
#pragma unroll
  for (int ct = 0; ct < 32; ++ct) o[ct] = (f4){0.f, 0.f, 0.f, 0.f};

  // prologue: stage tile 0 into buf 0 (linear 16B copies)
  {
    const unsigned short* img0 = W + ((size_t)(b * NT) << 15);
#pragma unroll
    for (int i = 0; i < 16; ++i) {
      U8 v = *(const U8*)(img0 + (i * 256 + tid) * 8);
      *(U8*)(sbuf[0] + (i * 256 + tid) * 8) = v;
    }
  }
  __syncthreads();

  int cb = 0;
  for (int t = 0; t < NT; ++t) {
    const bool pf = (t + 1 < NT);
    const unsigned short* imgn = W + ((size_t)(b * NT + t + 1) << 15);
    unsigned short* nb = sbuf[cb ^ 1];
    U8 st[8];
    // issue next-tile loads (first half: sK image) — latency hides under QK^T
    if (pf) {
#pragma unroll
      for (int i = 0; i < 8; ++i) st[i] = *(const U8*)(imgn + (i * 256 + tid) * 8);
    }

    // ---- QK^T: S[16 x 32] ----
    const unsigned short* sK = sbuf[cb];
    f4 s2[2];
    s2[0] = (f4){0.f, 0.f, 0.f, 0.f};
    s2[1] = (f4){0.f, 0.f, 0.f, 0.f};
#pragma unroll
    for (int ch = 0; ch < 16; ++ch) {
#pragma unroll
      for (int cc = 0; cc < 2; ++cc) {
        int key = cc * 16 + ll;
        int slot = (ch * 4 + lg) ^ (key & 7);
        bf8 kf = *(const bf8*)(sK + key * 512 + slot * 8);
        s2[cc] = __builtin_amdgcn_mfma_f32_16x16x32_bf16(qf[ch], kf, s2[cc], 0, 0, 0);
      }
    }

    // write half 1, issue half 2 (sVt image) — hides under softmax+PV
    if (pf) {
#pragma unroll
      for (int i = 0; i < 8; ++i) *(U8*)(nb + (i * 256 + tid) * 8) = st[i];
#pragma unroll
      for (int i = 0; i < 8; ++i) st[i] = *(const U8*)(imgn + ((i + 8) * 256 + tid) * 8);
    }

    // ---- online softmax ----
    float e2[2][4];
#pragma unroll
    for (int cc = 0; cc < 2; ++cc)
#pragma unroll
      for (int r = 0; r < 4; ++r)
        e2[cc][r] = s2[cc][r] * scale - bias[r];   // f32: masked rows -> exactly -1e9

    float tm[4];
#pragma unroll
    for (int r = 0; r < 4; ++r) tm[r] = fmaxf(e2[0][r], e2[1][r]);
#pragma unroll
    for (int off = 1; off < 16; off <<= 1)
#pragma unroll
      for (int r = 0; r < 4; ++r) tm[r] = fmaxf(tm[r], __shfl_xor(tm[r], off));

    float mn[4];
    bool change = false;
#pragma unroll
    for (int r = 0; r < 4; ++r) { mn[r] = fmaxf(m[r], tm[r]); change = change || (mn[r] > m[r]); }
    if (__any(change)) {
#pragma unroll
      for (int r = 0; r < 4; ++r) {
        float al = __expf(m[r] - mn[r]);
        lsum[r] *= al;
        m[r] = mn[r];
#pragma unroll
        for (int ct = 0; ct < 32; ++ct) o[ct][r] *= al;
      }
    }

    float ts[4] = {0.f, 0.f, 0.f, 0.f};
    unsigned short pb[2][4];
#pragma unroll
    for (int cc = 0; cc < 2; ++cc)
#pragma unroll
      for (int r = 0; r < 4; ++r) {
        float p = __expf(e2[cc][r] - m[r]);
        ts[r] += p;
        pb[cc][r] = f2bf(p);
      }
#pragma unroll
    for (int off = 1; off < 16; off <<= 1)
#pragma unroll
      for (int r = 0; r < 4; ++r) ts[r] += __shfl_xor(ts[r], off);
#pragma unroll
    for (int r = 0; r < 4; ++r) lsum[r] += ts[r];

    // ---- P round-trip (C-layout write, A-layout read; same wave) ----
    unsigned short* Pw = sP[wave];
#pragma unroll
    for (int cc = 0; cc < 2; ++cc)
#pragma unroll
      for (int r = 0; r < 4; ++r)
        Pw[(lg * 4 + r) * PP2 + cc * 16 + ll] = pb[cc][r];
    bf8 af = *(const bf8*)(Pw + ll * PP2 + lg * 8);

    // ---- PV: O[16 x 512] += P[16 x 32] * V[32 x 512] ----
    const unsigned short* sV = sbuf[cb] + 16384;
#pragma unroll
    for (int ct = 0; ct < 32; ++ct) {
      int d = ct * 16 + ll;
      bf8 vf = *(const bf8*)(sV + d * 32 + ((lg ^ ((d >> 1) & 3)) << 3));
      o[ct] = __builtin_amdgcn_mfma_f32_16x16x32_bf16(af, vf, o[ct], 0, 0, 0);
    }

    // write half 2 of next tile
    if (pf) {
#pragma unroll
      for (int i = 0; i < 8; ++i) *(U8*)(nb + ((i + 8) * 256 + tid) * 8) = st[i];
    }
    __syncthreads();
    cb ^= 1;
  }

  float inv[4];
#pragma unroll
  for (int r = 0; r < 4; ++r) inv[r] = 1.0f / lsum[r];
#pragma unroll
  for (int ct = 0; ct < 32; ++ct)
#pragma unroll
    for (int r = 0; r < 4; ++r) {
      size_t row = (size_t)b * Nn + q0 + lg * 4 + r;
      out[row * Dd + ct * 16 + ll] = o[ct][r] * inv[r];
    }
}

// ---------------------------------------------------------------------------
// Fallback: R10 structure (KV=64, in-kernel f32->bf16 convert, no ws needed)
// ---------------------------------------------------------------------------
__global__ __launch_bounds__(256, 1)
void attn_fb(const float* __restrict__ Xf, const int* __restrict__ mask,
             float* __restrict__ out) {
  __shared__ unsigned short sK[KVF * Dd];
  __shared__ unsigned short sVt[Dd * KVF];
  __shared__ unsigned short sPf[4][16 * PPF];

  const int tid  = threadIdx.x;
  const int wave = tid >> 6, lane = tid & 63;
  const int lg = lane >> 4, ll = lane & 15;
  const int b  = blockIdx.y;
  const int q0 = blockIdx.x * 64 + wave * 16;

  bf8 qf[16];
  {
    const size_t qoff = ((size_t)b * Nn + q0 + ll) * Dd;
#pragma unroll
    for (int ch = 0; ch < 16; ++ch) {
      int doff = ch * 32 + lg * 8;
      float4 a = *(const float4*)(Xf + qoff + doff);
      float4 c = *(const float4*)(Xf + qoff + doff + 4);
      bf8 tt;
      tt[0] = (short)f2bf(a.x); tt[1] = (short)f2bf(a.y);
      tt[2] = (short)f2bf(a.z); tt[3] = (short)f2bf(a.w);
      tt[4] = (short)f2bf(c.x); tt[5] = (short)f2bf(c.y);
      tt[6] = (short)f2bf(c.z); tt[7] = (short)f2bf(c.w);
      qf[ch] = tt;
    }
  }
  float bias[4];
#pragma unroll
  for (int r = 0; r < 4; ++r)
    bias[r] = (1.0f - (float)mask[b * Nn + q0 + lg * 4 + r]) * 1e9f;
  float m[4], lsum[4];
  f4 o[32];
#pragma unroll
  for (int r = 0; r < 4; ++r) { m[r] = -1e30f; lsum[r] = 0.0f; }
#pragma unroll
  for (int ct = 0; ct < 32; ++ct) o[ct] = (f4){0.f, 0.f, 0.f, 0.f};
  const float scale = 0.044194173824159216f;

  for (int t = 0; t < NTF; ++t) {
    __syncthreads();
    const size_t base = ((size_t)b * Nn + t * KVF) * Dd;
#pragma unroll
    for (int it = 0; it < 16; ++it) {
      int idx = it * 256 + tid;
      int key = idx >> 6, c = idx & 63;
      const float* sp = Xf + base + key * Dd + c * 8;
      float4 a = *(const float4*)(sp);
      float4 d2 = *(const float4*)(sp + 4);
      U8 v;
      v.s[0] = f2bf(a.x); v.s[1] = f2bf(a.y); v.s[2] = f2bf(a.z); v.s[3] = f2bf(a.w);
      v.s[4] = f2bf(d2.x); v.s[5] = f2bf(d2.y); v.s[6] = f2bf(d2.z); v.s[7] = f2bf(d2.w);
      *(U8*)(sK + key * 512 + ((c ^ (key & 7)) << 3)) = v;
      int ko = key >> 3, k7 = key & 7;
#pragma unroll
      for (int j = 0; j < 8; ++j) {
        int dd = c * 8 + j;
        sVt[dd * 64 + ((ko ^ j ^ (c & 7)) << 3) + k7] = v.s[j];
      }
    }
    __syncthreads();

    f4 s[4];
#pragma unroll
    for (int cc = 0; cc < 4; ++cc) s[cc] = (f4){0.f, 0.f, 0.f, 0.f};
#pragma unroll
    for (int ch = 0; ch < 16; ++ch)
#pragma unroll
      for (int cc = 0; cc < 4; ++cc) {
        int key = cc * 16 + ll;
        bf8 kf = *(const bf8*)(sK + key * 512 + (((ch * 4 + lg) ^ (key & 7)) << 3));
        s[cc] = __builtin_amdgcn_mfma_f32_16x16x32_bf16(qf[ch], kf, s[cc], 0, 0, 0);
      }

    float e[4][4];
#pragma unroll
    for (int cc = 0; cc < 4; ++cc)
#pragma unroll
      for (int r = 0; r < 4; ++r) e[cc][r] = s[cc][r] * scale - bias[r];
    float tm[4];
#pragma unroll
    for (int r = 0; r < 4; ++r)
      tm[r] = fmaxf(fmaxf(e[0][r], e[1][r]), fmaxf(e[2][r], e[3][r]));
#pragma unroll
    for (int off = 1; off < 16; off <<= 1)
#pragma unroll
      for (int r = 0; r < 4; ++r) tm[r] = fmaxf(tm[r], __shfl_xor(tm[r], off));
    float mn[4]; bool change = false;
#pragma unroll
    for (int r = 0; r < 4; ++r) { mn[r] = fmaxf(m[r], tm[r]); change = change || (mn[r] > m[r]); }
    if (__any(change)) {
#pragma unroll
      for (int r = 0; r < 4; ++r) {
        float al = __expf(m[r] - mn[r]);
        lsum[r] *= al; m[r] = mn[r];
#pragma unroll
        for (int ct = 0; ct < 32; ++ct) o[ct][r] *= al;
      }
    }
    float ts[4] = {0.f, 0.f, 0.f, 0.f};
    unsigned short pb[4][4];
#pragma unroll
    for (int cc = 0; cc < 4; ++cc)
#pragma unroll
      for (int r = 0; r < 4; ++r) {
        float p = __expf(e[cc][r] - m[r]);
        ts[r] += p; pb[cc][r] = f2bf(p);
      }
#pragma unroll
    for (int off = 1; off < 16; off <<= 1)
#pragma unroll
      for (int r = 0; r < 4; ++r) ts[r] += __shfl_xor(ts[r], off);
#pragma unroll
    for (int r = 0; r < 4; ++r) lsum[r] += ts[r];

    unsigned short* Pw = sPf[wave];
#pragma unroll
    for (int cc = 0; cc < 4; ++cc)
#pragma unroll
      for (int r = 0; r < 4; ++r)
        Pw[(lg * 4 + r) * PPF + cc * 16 + ll] = pb[cc][r];
#pragma unroll
    for (int kc = 0; kc < 2; ++kc) {
      bf8 af = *(const bf8*)(Pw + ll * PPF + kc * 32 + lg * 8);
#pragma unroll
      for (int ct = 0; ct < 32; ++ct) {
        int d = ct * 16 + ll;
        bf8 vf = *(const bf8*)(sVt + d * 64 + (((kc * 4 + lg) ^ (d & 7) ^ ((d >> 3) & 7)) << 3));
        o[ct] = __builtin_amdgcn_mfma_f32_16x16x32_bf16(af, vf, o[ct], 0, 0, 0);
      }
    }
  }
  float inv[4];
#pragma unroll
  for (int r = 0; r < 4; ++r) inv[r] = 1.0f / lsum[r];
#pragma unroll
  for (int ct = 0; ct < 32; ++ct)
#pragma unroll
    for (int r = 0; r < 4; ++r) {
      size_t row = (size_t)b * Nn + q0 + lg * 4 + r;
      out[row * Dd + ct * 16 + ll] = o[ct][r] * inv[r];
    }
}

extern "C" void kernel_launch(void* const* d_in, const int* in_sizes, int n_in,
                              void* d_out, int out_size, void* d_ws, size_t ws_size,
                              hipStream_t stream) {
  (void)in_sizes; (void)n_in; (void)out_size;
  const float* X  = (const float*)d_in[0];
  const int* mask = (const int*)d_in[1];
  float* out = (float*)d_out;

  const size_t need = (size_t)Bb * NT * 65536;  // 32 MB of bf16 images
  if (ws_size >= need) {
    unsigned short* W = (unsigned short*)d_ws;
    build_images<<<dim3(NT, Bb), 256, 0, stream>>>(X, W);
    attn_fast<<<256, 256, 0, stream>>>(W, mask, out);
  } else {
    attn_fb<<<dim3(Nn / 64, Bb), 256, 0, stream>>>(X, mask, out);
  }
}